// Round 1
// baseline (209.479 us; speedup 1.0000x reference)
//
#include <hip/hip_runtime.h>
#include <math.h>

#define S_LEN 262144
#define N 128
#define TPB 256
#define GRID 512
#define NWAVES (GRID * 4)          // 2048 waves == exactly resident at 2 waves/SIMD
#define ITEMS (S_LEN / 16)         // one item = full 16-row x 128-col strip = 16384 items

typedef __attribute__((ext_vector_type(8))) short bf16x8;
typedef __attribute__((ext_vector_type(4))) float f32x4;

__device__ __forceinline__ unsigned short f2bf(float x) {
    unsigned b = __float_as_uint(x);
    b = (b + 0x7FFF + ((b >> 16) & 1)) >> 16;   // RNE to bf16
    return (unsigned short)b;
}
__device__ __forceinline__ float bf2f(unsigned short u) {
    return __uint_as_float((unsigned)u << 16);
}
// low16 = bf16(x), high16 = bf16(y) (round-half-up): 2 adds + 1 perm
__device__ __forceinline__ unsigned pack2bf(float x, float y) {
    return __builtin_amdgcn_perm(__float_as_uint(y) + 0x8000u,
                                 __float_as_uint(x) + 0x8000u, 0x07060302u);
}
__device__ __forceinline__ float wave_reduce(float v) {
    #pragma unroll
    for (int off = 32; off > 0; off >>= 1) v += __shfl_down(v, off, 64);
    return v;
}
// intra-wave LDS ordering fence: drain DS queue + stop compiler reordering.
// Does NOT touch vmcnt (global loads stay in flight) and is NOT a barrier.
__device__ __forceinline__ void lds_fence() {
    asm volatile("s_waitcnt lgkmcnt(0)" ::: "memory");
}

// M = W_K^T @ W_Q (128x128) fp32; emit bf16 in MFMA-B-fragment order:
//   frag[((kk*8 + ct)*64 + lane)*8 + j] = M[kk*32 + (lane>>4)*8 + j][ct*16 + (lane&15)]
// l1 = sum(sigmoid(M)) -> out[1].
__global__ void mk_kernel(const float* __restrict__ WQ, const float* __restrict__ WK,
                          unsigned short* __restrict__ fragB, float* __restrict__ out) {
    const int i = blockIdx.x;   // M row (k of main GEMM) -- uniform => scalar loads
    const int j = threadIdx.x;  // M col
    float acc = 0.f;
    #pragma unroll 8
    for (int r = 0; r < N; ++r) acc = fmaf(WK[r * N + i], WQ[r * N + j], acc);

    const int kk = i >> 5, q = (i >> 3) & 3, jj = i & 7;
    const int ct = j >> 4, n15 = j & 15;
    fragB[((kk * 8 + ct) * 64 + (q * 16 + n15)) * 8 + jj] = f2bf(acc);

    float sg = fabsf(1.0f / (1.0f + __expf(-acc)));
    float ws = wave_reduce(sg);
    __shared__ float red[2];
    if ((j & 63) == 0) red[j >> 6] = ws;
    __syncthreads();
    if (j == 0) atomicAdd(&out[1], red[0] + red[1]);
}

// Wave-autonomous: each wave owns a full strip of 16 rows x ALL 128 cols, so the
// 16x128 A-tile (the GEMM K-dim needs all 128 input cols) is fetched from HBM
// exactly ONCE -- the previous 64-col split fetched every strip twice.
// No cross-wave barriers in the main loop; per-wave private LDS strip; global
// loads straight to VGPRs; intra-wave lgkm fences order the LDS round-trip.
__global__ __launch_bounds__(TPB, 2) void main_kernel(
    const float* __restrict__ In, const unsigned short* __restrict__ fragB,
    float* __restrict__ out, float inv_denom) {
    __shared__ unsigned short sA[4][17][132];   // per-wave strip: 16 rows + boundary row
    __shared__ float sRed[4];

    const int tid = threadIdx.x;
    const int w = tid >> 6, lane = tid & 63;
    const int q = lane >> 4, n15 = lane & 15;
    const int gid = blockIdx.x * 4 + w;          // global wave id

    // B fragments for all 128 cols (ct = 0..7), constant all kernel (128 VGPRs)
    bf16x8 bF[8][4];
    #pragma unroll
    for (int c4 = 0; c4 < 8; ++c4)
        #pragma unroll
        for (int kk = 0; kk < 4; ++kk)
            bF[c4][kk] = *(const bf16x8*)&fragB[((kk * 8 + c4) * 64 + lane) * 8];

    bf16x8 bOne;   // all-ones B: rowsum via MFMA, C/D layout matches epilogue
    #pragma unroll
    for (int e = 0; e < 8; ++e) bOne[e] = (short)0x3F80;

    unsigned short (*my)[132] = sA[w];
    float lsum = 0.f;
    float4 r[8];
    float2 x;

    auto issue = [&](int item) {
        const long r0 = (long)item * 16;
        const float* base = In + r0 * N;
        #pragma unroll
        for (int j = 0; j < 8; ++j)              // 8 x 1KB chunks: rows 2j, 2j+1
            r[j] = *(const float4*)(base + j * 256 + lane * 4);
        long rX = r0 + 16; if (rX > S_LEN - 1) rX = S_LEN - 1;
        x = *(const float2*)&In[rX * N + lane * 2];   // boundary row, all 64 lanes
    };

    int item = gid;
    issue(item);

    while (item < ITEMS) {
        const int next = item + NWAVES;

        // pack fp32 regs -> bf16 LDS strip (compiler inserts vmcnt waits for r/x)
        #pragma unroll
        for (int j = 0; j < 8; ++j) {
            const int row = 2 * j + (lane >> 5);
            const int c = lane & 31;
            *(unsigned int*)&my[row][c * 4] = pack2bf(r[j].x, r[j].y);
            *(unsigned int*)&my[row][c * 4 + 2] = pack2bf(r[j].z, r[j].w);
        }
        *(unsigned int*)&my[16][lane * 2] = pack2bf(x.x, x.y);

        // immediately put next item's loads in flight (r, x now dead)
        if (next < ITEMS) issue(next);

        lds_fence();   // pack visible to all lanes of this wave before fragment reads

        // MFMA: z (8 col-tiles) + rowsum, K=128
        f32x4 acc[8], aRS;
        aRS = (f32x4){0.f, 0.f, 0.f, 0.f};
        #pragma unroll
        for (int c4 = 0; c4 < 8; ++c4) acc[c4] = (f32x4){0.f, 0.f, 0.f, 0.f};
        #pragma unroll
        for (int kk = 0; kk < 4; ++kk) {
            bf16x8 a = *(const bf16x8*)&my[n15][kk * 32 + q * 8];  // A[m=n15][k=q*8+j]
            aRS = __builtin_amdgcn_mfma_f32_16x16x32_bf16(a, bOne, aRS, 0, 0, 0);
            #pragma unroll
            for (int c4 = 0; c4 < 8; ++c4)
                acc[c4] = __builtin_amdgcn_mfma_f32_16x16x32_bf16(a, bF[c4][kk], acc[c4], 0, 0, 0);
        }

        // epilogue: C/D row = q*4+reg, col = n15 (per 16-tile)
        const long r0 = (long)item * 16;
        #pragma unroll
        for (int reg = 0; reg < 4; ++reg) {
            const int row = q * 4 + reg;
            const float rs = aRS[reg];
            const long s = r0 + row;
            const bool has = (s < S_LEN - 1);
            #pragma unroll
            for (int c4 = 0; c4 < 8; ++c4) {
                const float z = acc[c4][reg];
                const float sp = fmaxf(z, 0.f) + __logf(1.0f + __expf(-fabsf(z)));
                const float o = sp * rs;
                if (has) {
                    const int col = c4 * 16 + n15;
                    const float d = o - bf2f(my[row + 1][col]);
                    lsum = fmaf(d, d, lsum);
                }
            }
        }

        lds_fence();   // epilogue LDS reads done before next iteration's pack overwrites
        item = next;
    }

    const float wsum = wave_reduce(lsum);
    if ((tid & 63) == 0) sRed[w] = wsum;
    __syncthreads();
    if (tid == 0) {
        float t = 0.f;
        #pragma unroll
        for (int w2 = 0; w2 < 4; ++w2) t += sRed[w2];
        atomicAdd(&out[0], t * inv_denom);
    }
}

extern "C" void kernel_launch(void* const* d_in, const int* in_sizes, int n_in,
                              void* d_out, int out_size, void* d_ws, size_t ws_size,
                              hipStream_t stream) {
    const float* In = (const float*)d_in[0];
    const float* WQ = (const float*)d_in[1];
    const float* WK = (const float*)d_in[2];
    float* out = (float*)d_out;
    unsigned short* fragB = (unsigned short*)d_ws;   // 32 KB

    hipMemsetAsync(d_out, 0, 2 * sizeof(float), stream);
    mk_kernel<<<128, 128, 0, stream>>>(WQ, WK, fragB, out);
    const float inv = (float)(1.0 / ((double)(S_LEN - 1) * (double)N));
    main_kernel<<<GRID, TPB, 0, stream>>>(In, fragB, out, inv);
}

// Round 2
// 202.319 us; speedup vs baseline: 1.0354x; 1.0354x over previous
//
#include <hip/hip_runtime.h>
#include <math.h>

#define S_LEN 262144
#define N 128
#define TPB 256
#define GRID 768
#define NWAVES (GRID * 4)          // 3072 waves
#define ITEMS (S_LEN / 16 * 2)     // strip(16 rows) x col-half = 32768 items

typedef __attribute__((ext_vector_type(8))) short bf16x8;
typedef __attribute__((ext_vector_type(4))) float f32x4;

__device__ __forceinline__ unsigned short f2bf(float x) {
    unsigned b = __float_as_uint(x);
    b = (b + 0x7FFF + ((b >> 16) & 1)) >> 16;   // RNE to bf16
    return (unsigned short)b;
}
__device__ __forceinline__ float bf2f(unsigned short u) {
    return __uint_as_float((unsigned)u << 16);
}
// low16 = bf16(x), high16 = bf16(y) (round-half-up): 2 adds + 1 perm
__device__ __forceinline__ unsigned pack2bf(float x, float y) {
    return __builtin_amdgcn_perm(__float_as_uint(y) + 0x8000u,
                                 __float_as_uint(x) + 0x8000u, 0x07060302u);
}
__device__ __forceinline__ float wave_reduce(float v) {
    #pragma unroll
    for (int off = 32; off > 0; off >>= 1) v += __shfl_down(v, off, 64);
    return v;
}
// intra-wave LDS ordering fence: drain DS queue + stop compiler reordering.
// Does NOT touch vmcnt (global loads stay in flight) and is NOT a barrier.
__device__ __forceinline__ void lds_fence() {
    asm volatile("s_waitcnt lgkmcnt(0)" ::: "memory");
}

// M = W_K^T @ W_Q (128x128) fp32; emit bf16 in MFMA-B-fragment order:
//   frag[((kk*8 + ct)*64 + lane)*8 + j] = M[kk*32 + (lane>>4)*8 + j][ct*16 + (lane&15)]
// l1 partials (sum sigmoid(M) per block) -> wsP[block]; out[0] zeroed here so
// main_kernel's atomics land on a clean slate (kernel-boundary ordering).
// Full unroll + 4 accumulator chains: keeps ~32+ cold-HBM loads in flight
// (the old "#pragma unroll 8" single-chain version was latency-bound,
// ~16 serial 900ns windows for a 4-MFLOP matmul).
__global__ void mk_kernel(const float* __restrict__ WQ, const float* __restrict__ WK,
                          unsigned short* __restrict__ fragB, float* __restrict__ wsP,
                          float* __restrict__ out) {
    const int i = blockIdx.x;   // M row (k of main GEMM) -- uniform => scalar loads
    const int j = threadIdx.x;  // M col
    float a0 = 0.f, a1 = 0.f, a2 = 0.f, a3 = 0.f;
    #pragma unroll
    for (int r = 0; r < N; r += 4) {
        a0 = fmaf(WK[(r + 0) * N + i], WQ[(r + 0) * N + j], a0);
        a1 = fmaf(WK[(r + 1) * N + i], WQ[(r + 1) * N + j], a1);
        a2 = fmaf(WK[(r + 2) * N + i], WQ[(r + 2) * N + j], a2);
        a3 = fmaf(WK[(r + 3) * N + i], WQ[(r + 3) * N + j], a3);
    }
    const float acc = (a0 + a1) + (a2 + a3);

    const int kk = i >> 5, q = (i >> 3) & 3, jj = i & 7;
    const int ct = j >> 4, n15 = j & 15;
    fragB[((kk * 8 + ct) * 64 + (q * 16 + n15)) * 8 + jj] = f2bf(acc);

    float sg = fabsf(1.0f / (1.0f + __expf(-acc)));
    float ws = wave_reduce(sg);
    __shared__ float red[2];
    if ((j & 63) == 0) red[j >> 6] = ws;
    __syncthreads();
    if (j == 0) wsP[i] = red[0] + red[1];
    if (i == 0 && j == 0) out[0] = 0.f;
}

// Wave-autonomous: each wave owns (strip of 16 rows) x (64 cols). The duplicate
// strip read by the paired col-half wave is an L2/L3 hit (Input = 134 MB < 256 MB
// Infinity Cache; paired gids run concurrently), so HBM fetch stays ~134 MB.
// No cross-wave barriers in the main loop; per-wave private LDS strip; global
// loads straight to VGPRs; intra-wave lgkm fences order the LDS round-trip.
__global__ __launch_bounds__(TPB, 3) void main_kernel(
    const float* __restrict__ In, const unsigned short* __restrict__ fragB,
    const float* __restrict__ wsP, float* __restrict__ out, float inv_denom) {
    __shared__ unsigned short sA[4][17][132];   // per-wave strip: 16 rows + boundary row
    __shared__ float sRed[4];

    const int tid = threadIdx.x;
    const int w = tid >> 6, lane = tid & 63;
    const int q = lane >> 4, n15 = lane & 15;
    const int gid = blockIdx.x * 4 + w;          // global wave id
    const int half = gid & 1;                    // col half (item stride is even)

    unsigned short (*my)[132] = sA[w];
    float lsum = 0.f;
    float4 r[8];
    float2 x;

    auto issue = [&](int item) {
        const long r0 = (long)(item >> 1) * 16;
        const float* base = In + r0 * N;
        #pragma unroll
        for (int j = 0; j < 8; ++j)              // 8 x 1KB chunks: rows 2j, 2j+1
            r[j] = *(const float4*)(base + j * 256 + lane * 4);
        long rX = r0 + 16; if (rX > S_LEN - 1) rX = S_LEN - 1;
        x = *(const float2*)&In[rX * N + lane * 2];   // boundary row, all 64 lanes
    };

    // put the first item's HBM loads in flight BEFORE touching fragB: the
    // fragment loads (L2-resident, mk just wrote them) hide under HBM latency
    int item = gid;
    issue(item);

    // B fragments for this wave's 64 cols (ct = half*4 + c4), constant all kernel
    bf16x8 bF[4][4];
    #pragma unroll
    for (int c4 = 0; c4 < 4; ++c4)
        #pragma unroll
        for (int kk = 0; kk < 4; ++kk)
            bF[c4][kk] = *(const bf16x8*)&fragB[((kk * 8 + (half * 4 + c4)) * 64 + lane) * 8];

    bf16x8 bOne;   // all-ones B: rowsum via MFMA, C/D layout matches epilogue
    #pragma unroll
    for (int e = 0; e < 8; ++e) bOne[e] = (short)0x3F80;

    // block 0, wave 0: finalize l1 from mk's 128 per-block partials (single writer)
    if (blockIdx.x == 0 && w == 0) {
        float p = wsP[lane] + wsP[lane + 64];
        float s = wave_reduce(p);
        if (lane == 0) out[1] = s;
    }

    while (item < ITEMS) {
        const int next = item + NWAVES;

        // pack fp32 regs -> bf16 LDS strip (compiler inserts vmcnt waits for r/x)
        #pragma unroll
        for (int j = 0; j < 8; ++j) {
            const int row = 2 * j + (lane >> 5);
            const int c = lane & 31;
            *(unsigned int*)&my[row][c * 4] = pack2bf(r[j].x, r[j].y);
            *(unsigned int*)&my[row][c * 4 + 2] = pack2bf(r[j].z, r[j].w);
        }
        *(unsigned int*)&my[16][lane * 2] = pack2bf(x.x, x.y);

        // immediately put next item's loads in flight (r, x now dead)
        if (next < ITEMS) issue(next);

        lds_fence();   // pack visible to all lanes of this wave before fragment reads

        // MFMA: z (4 col-tiles) + rowsum, K=128
        f32x4 acc[4], aRS;
        aRS = (f32x4){0.f, 0.f, 0.f, 0.f};
        #pragma unroll
        for (int c4 = 0; c4 < 4; ++c4) acc[c4] = (f32x4){0.f, 0.f, 0.f, 0.f};
        #pragma unroll
        for (int kk = 0; kk < 4; ++kk) {
            bf16x8 a = *(const bf16x8*)&my[n15][kk * 32 + q * 8];  // A[m=n15][k=q*8+j]
            aRS = __builtin_amdgcn_mfma_f32_16x16x32_bf16(a, bOne, aRS, 0, 0, 0);
            #pragma unroll
            for (int c4 = 0; c4 < 4; ++c4)
                acc[c4] = __builtin_amdgcn_mfma_f32_16x16x32_bf16(a, bF[c4][kk], acc[c4], 0, 0, 0);
        }

        // epilogue: C/D row = q*4+reg, col = n15 (per 16-tile)
        const long r0 = (long)(item >> 1) * 16;
        #pragma unroll
        for (int reg = 0; reg < 4; ++reg) {
            const int row = q * 4 + reg;
            const float rs = aRS[reg];
            const long s = r0 + row;
            const bool has = (s < S_LEN - 1);
            #pragma unroll
            for (int c4 = 0; c4 < 4; ++c4) {
                const float z = acc[c4][reg];
                const float sp = fmaxf(z, 0.f) + __logf(1.0f + __expf(-fabsf(z)));
                const float o = sp * rs;
                if (has) {
                    const int col = half * 64 + c4 * 16 + n15;
                    const float d = o - bf2f(my[row + 1][col]);
                    lsum = fmaf(d, d, lsum);
                }
            }
        }

        lds_fence();   // epilogue LDS reads done before next iteration's pack overwrites
        item = next;
    }

    const float wsum = wave_reduce(lsum);
    if ((tid & 63) == 0) sRed[w] = wsum;
    __syncthreads();
    if (tid == 0) {
        float t = 0.f;
        #pragma unroll
        for (int w2 = 0; w2 < 4; ++w2) t += sRed[w2];
        atomicAdd(&out[0], t * inv_denom);
    }
}

extern "C" void kernel_launch(void* const* d_in, const int* in_sizes, int n_in,
                              void* d_out, int out_size, void* d_ws, size_t ws_size,
                              hipStream_t stream) {
    const float* In = (const float*)d_in[0];
    const float* WQ = (const float*)d_in[1];
    const float* WK = (const float*)d_in[2];
    float* out = (float*)d_out;
    unsigned short* fragB = (unsigned short*)d_ws;          // 32 KB
    float* wsP = (float*)((char*)d_ws + 32 * 1024);         // 128 floats: l1 partials

    mk_kernel<<<128, 128, 0, stream>>>(WQ, WK, fragB, wsP, out);
    const float inv = (float)(1.0 / ((double)(S_LEN - 1) * (double)N));
    main_kernel<<<GRID, TPB, 0, stream>>>(In, fragB, wsP, out, inv);
}